// Round 1
// baseline (334.379 us; speedup 1.0000x reference)
//
#include <hip/hip_runtime.h>
#include <hip/hip_fp16.h>
#include <stdint.h>

#define TOKENS 4096
#define HDIM   2048
#define IDIM   5632
#define BM 128
#define BN 128
#define BK 64

typedef _Float16 f16x8 __attribute__((ext_vector_type(8)));
typedef float    f32x4 __attribute__((ext_vector_type(4)));

// Decode two fp4 (e2m1) values sitting at bits [3:0] and [19:16] of z into two
// f16 halves, multiplied by s2u = packed f16 (scale * 2^14, scale * 2^14).
// f16 = sign | (e2m1 em bits << 9). For e>=1 value = 2^(e-15)*(1+m/2);
// e==0 gives f16 subnormal m*2^-15 (exact 0 / 0.5 after the 2^14 scale fold).
__device__ __forceinline__ uint32_t dec2(uint32_t z, uint32_t s2u) {
    uint32_t sgn = (z << 12) & 0x80008000u;
    uint32_t h   = ((z << 9) & 0x0E000E00u) | sgn;
    __half2 hv = __builtin_bit_cast(__half2, h);
    __half2 sv = __builtin_bit_cast(__half2, s2u);
    __half2 r  = __hmul2(hv, sv);
    return __builtin_bit_cast(uint32_t, r);
}

__device__ __forceinline__ uint32_t packh(float lo, float hi) {
    __half2 h2 = __halves2half2(__float2half(lo), __float2half(hi));
    return __builtin_bit_cast(uint32_t, h2);
}

// hidden fp32 -> f16, with the sigma k-permutation within each 8-group:
// storage position p holds logical k: (0,4,1,5,2,6,3,7) — matches the
// (j, j+4) pair order the SWAR fp4 decode naturally produces.
__global__ __launch_bounds__(256) void convert_hidden(
    const float* __restrict__ src, __half* __restrict__ dst)
{
    int idx = blockIdx.x * 256 + threadIdx.x;   // one 8-group per thread
    const float4* s = (const float4*)src + (size_t)idx * 2;
    float4 a = s[0], b = s[1];                  // a = x0..x3, b = x4..x7
    int4 v;
    v.x = (int)packh(a.x, b.x);                 // pos 0,1 = x0,x4
    v.y = (int)packh(a.y, b.y);                 // pos 2,3 = x1,x5
    v.z = (int)packh(a.z, b.z);
    v.w = (int)packh(a.w, b.w);
    *((int4*)dst + idx) = v;
}

// GEMM1: act[m][n] = silu(h @ Wg)[m][n] * (h @ Wu)[m][n], n in [0,IDIM)
// A: [4096][2048] f16 (sigma-permuted k). W packed fp4 [256][11264], S [16][11264].
__global__ __launch_bounds__(256, 2) void gemm1_silu(
    const __half* __restrict__ A, const uint32_t* __restrict__ W,
    const float* __restrict__ S, __half* __restrict__ act)
{
    __shared__ __half Alds[BM * BK];
    __shared__ __half Blds[2][BN * BK];
    const int tid  = threadIdx.x;
    const int lane = tid & 63;
    const int wid  = tid >> 6;
    const int wm = wid >> 1, wn = wid & 1;
    const int m0 = blockIdx.y * BM;
    const int c0 = blockIdx.x * BN;

    f32x4 accg[4][4], accu[4][4];
    #pragma unroll
    for (int i = 0; i < 4; ++i)
        #pragma unroll
        for (int j = 0; j < 4; ++j) {
            accg[i][j] = f32x4{0.f, 0.f, 0.f, 0.f};
            accu[i][j] = f32x4{0.f, 0.f, 0.f, 0.f};
        }

    const int c = tid & 127;              // B column within tile
    const int rbase = (tid >> 7) * 4;     // packed-word row base (0 or 4)

    for (int kt = 0; kt < HDIM / BK; ++kt) {
        const int k0 = kt * BK;
        // ---- stage A: 128x64 f16, XOR-swizzled 16B blocks ----
        #pragma unroll
        for (int i = 0; i < 4; ++i) {
            int u = tid + i * 256;
            int row = u >> 3, kb = u & 7;
            int4 v = *(const int4*)(A + (size_t)(m0 + row) * HDIM + k0 + kb * 8);
            *(int4*)((char*)Alds + row * 128 + ((kb ^ (row & 7)) << 4)) = v;
        }
        // ---- stage B: dequant fp4 -> f16, two panels (gate, up) ----
        const int g = k0 >> 7;            // scale group row
        #pragma unroll
        for (int p = 0; p < 2; ++p) {
            const int ncol = (p ? IDIM : 0) + c0 + c;
            float sc = S[(size_t)g * (2 * IDIM) + ncol] * 16384.0f;
            uint16_t hs = __builtin_bit_cast(uint16_t, __float2half(sc));
            uint32_t s2u = (uint32_t)hs * 0x00010001u;
            #pragma unroll
            for (int i = 0; i < 4; ++i) {
                int rl = rbase + i;
                uint32_t w = W[(size_t)(kt * 8 + rl) * (2 * IDIM) + ncol];
                int4 d;
                d.x = (int)dec2( w        & 0x000F000Fu, s2u);
                d.y = (int)dec2((w >> 4)  & 0x000F000Fu, s2u);
                d.z = (int)dec2((w >> 8)  & 0x000F000Fu, s2u);
                d.w = (int)dec2((w >> 12) & 0x000F000Fu, s2u);
                *(int4*)((char*)&Blds[p][0] + c * 128 + ((rl ^ (c & 7)) << 4)) = d;
            }
        }
        __syncthreads();
        // ---- MFMA: each wave 64x64 output, dual accumulators ----
        #pragma unroll
        for (int ks = 0; ks < 2; ++ks) {
            f16x8 af[4], bg[4], bu[4];
            const int kb = ks * 4 + (lane >> 4);
            #pragma unroll
            for (int mi = 0; mi < 4; ++mi) {
                int m = wm * 64 + mi * 16 + (lane & 15);
                af[mi] = *(const f16x8*)((const char*)Alds + m * 128 + ((kb ^ (m & 7)) << 4));
            }
            #pragma unroll
            for (int ni = 0; ni < 4; ++ni) {
                int n = wn * 64 + ni * 16 + (lane & 15);
                bg[ni] = *(const f16x8*)((const char*)&Blds[0][0] + n * 128 + ((kb ^ (n & 7)) << 4));
                bu[ni] = *(const f16x8*)((const char*)&Blds[1][0] + n * 128 + ((kb ^ (n & 7)) << 4));
            }
            #pragma unroll
            for (int mi = 0; mi < 4; ++mi)
                #pragma unroll
                for (int ni = 0; ni < 4; ++ni) {
                    accg[mi][ni] = __builtin_amdgcn_mfma_f32_16x16x32_f16(af[mi], bg[ni], accg[mi][ni], 0, 0, 0);
                    accu[mi][ni] = __builtin_amdgcn_mfma_f32_16x16x32_f16(af[mi], bu[ni], accu[mi][ni], 0, 0, 0);
                }
        }
        __syncthreads();
    }
    // ---- epilogue: silu(gate)*up -> act f16, sigma-permuted column slot ----
    #pragma unroll
    for (int mi = 0; mi < 4; ++mi) {
        #pragma unroll
        for (int ni = 0; ni < 4; ++ni) {
            int nlog = c0 + wn * 64 + ni * 16 + (lane & 15);
            int ncol = (nlog & ~7) | (((nlog & 3) << 1) | ((nlog >> 2) & 1));
            #pragma unroll
            for (int r = 0; r < 4; ++r) {
                int m = m0 + wm * 64 + mi * 16 + (lane >> 4) * 4 + r;
                float gv = accg[mi][ni][r];
                float uv = accu[mi][ni][r];
                float sig = 1.0f / (1.0f + __expf(-gv));
                act[(size_t)m * IDIM + ncol] = __float2half(gv * sig * uv);
            }
        }
    }
}

// GEMM2: out = moe + act @ dequant(Wd).  act [4096][5632] f16 (sigma k-order),
// Wd [704][2048] packed, Sd [44][2048], out fp32.
__global__ __launch_bounds__(256, 2) void gemm2_add(
    const __half* __restrict__ A, const uint32_t* __restrict__ W,
    const float* __restrict__ S, const float* __restrict__ moe,
    float* __restrict__ out)
{
    __shared__ __half Alds[BM * BK];
    __shared__ __half Blds[BN * BK];
    const int tid  = threadIdx.x;
    const int lane = tid & 63;
    const int wid  = tid >> 6;
    const int wm = wid >> 1, wn = wid & 1;
    const int m0 = blockIdx.y * BM;
    const int n0 = blockIdx.x * BN;

    f32x4 acc[4][4];
    #pragma unroll
    for (int i = 0; i < 4; ++i)
        #pragma unroll
        for (int j = 0; j < 4; ++j) acc[i][j] = f32x4{0.f, 0.f, 0.f, 0.f};

    const int c = tid & 127;
    const int rbase = (tid >> 7) * 4;

    for (int kt = 0; kt < IDIM / BK; ++kt) {
        const int k0 = kt * BK;
        #pragma unroll
        for (int i = 0; i < 4; ++i) {
            int u = tid + i * 256;
            int row = u >> 3, kb = u & 7;
            int4 v = *(const int4*)(A + (size_t)(m0 + row) * IDIM + k0 + kb * 8);
            *(int4*)((char*)Alds + row * 128 + ((kb ^ (row & 7)) << 4)) = v;
        }
        {
            const int g = k0 >> 7;
            const int ncol = n0 + c;
            float sc = S[(size_t)g * HDIM + ncol] * 16384.0f;
            uint16_t hs = __builtin_bit_cast(uint16_t, __float2half(sc));
            uint32_t s2u = (uint32_t)hs * 0x00010001u;
            #pragma unroll
            for (int i = 0; i < 4; ++i) {
                int rl = rbase + i;
                uint32_t w = W[(size_t)(kt * 8 + rl) * HDIM + ncol];
                int4 d;
                d.x = (int)dec2( w        & 0x000F000Fu, s2u);
                d.y = (int)dec2((w >> 4)  & 0x000F000Fu, s2u);
                d.z = (int)dec2((w >> 8)  & 0x000F000Fu, s2u);
                d.w = (int)dec2((w >> 12) & 0x000F000Fu, s2u);
                *(int4*)((char*)Blds + c * 128 + ((rl ^ (c & 7)) << 4)) = d;
            }
        }
        __syncthreads();
        #pragma unroll
        for (int ks = 0; ks < 2; ++ks) {
            f16x8 af[4], bf[4];
            const int kb = ks * 4 + (lane >> 4);
            #pragma unroll
            for (int mi = 0; mi < 4; ++mi) {
                int m = wm * 64 + mi * 16 + (lane & 15);
                af[mi] = *(const f16x8*)((const char*)Alds + m * 128 + ((kb ^ (m & 7)) << 4));
            }
            #pragma unroll
            for (int ni = 0; ni < 4; ++ni) {
                int n = wn * 64 + ni * 16 + (lane & 15);
                bf[ni] = *(const f16x8*)((const char*)Blds + n * 128 + ((kb ^ (n & 7)) << 4));
            }
            #pragma unroll
            for (int mi = 0; mi < 4; ++mi)
                #pragma unroll
                for (int ni = 0; ni < 4; ++ni)
                    acc[mi][ni] = __builtin_amdgcn_mfma_f32_16x16x32_f16(af[mi], bf[ni], acc[mi][ni], 0, 0, 0);
        }
        __syncthreads();
    }
    #pragma unroll
    for (int mi = 0; mi < 4; ++mi) {
        #pragma unroll
        for (int ni = 0; ni < 4; ++ni) {
            int n = n0 + wn * 64 + ni * 16 + (lane & 15);
            #pragma unroll
            for (int r = 0; r < 4; ++r) {
                int m = m0 + wm * 64 + mi * 16 + (lane >> 4) * 4 + r;
                out[(size_t)m * HDIM + n] = moe[(size_t)m * HDIM + n] + acc[mi][ni][r];
            }
        }
    }
}

extern "C" void kernel_launch(void* const* d_in, const int* in_sizes, int n_in,
                              void* d_out, int out_size, void* d_ws, size_t ws_size,
                              hipStream_t stream) {
    const float*    hidden = (const float*)d_in[0];
    const float*    moe    = (const float*)d_in[1];
    const uint32_t* wgu    = (const uint32_t*)d_in[2];
    const float*    sgu    = (const float*)d_in[3];
    const uint32_t* wd     = (const uint32_t*)d_in[4];
    const float*    sd     = (const float*)d_in[5];
    float* out = (float*)d_out;

    __half* hidden_f16 = (__half*)d_ws;                                   // 16.78 MB
    __half* act        = (__half*)((char*)d_ws + (size_t)TOKENS * HDIM * 2); // 46.14 MB

    convert_hidden<<<dim3(TOKENS * HDIM / 8 / 256), dim3(256), 0, stream>>>(hidden, hidden_f16);
    gemm1_silu<<<dim3(IDIM / BN, TOKENS / BM), dim3(256), 0, stream>>>(hidden_f16, wgu, sgu, act);
    gemm2_add<<<dim3(HDIM / BN, TOKENS / BM), dim3(256), 0, stream>>>(act, wd, sd, moe, out);
}